// Round 18
// baseline (1328.180 us; speedup 1.0000x reference)
//
#include <hip/hip_runtime.h>
#include <math.h>

#define LEAK 0.2f

typedef __attribute__((ext_vector_type(8))) short bf16x8;
typedef __attribute__((ext_vector_type(4))) float f32x4;

__device__ __forceinline__ unsigned short f2bf(float f) {
  unsigned u = __float_as_uint(f);
  u += 0x7FFFu + ((u >> 16) & 1u);
  return (unsigned short)(u >> 16);
}
__device__ __forceinline__ unsigned pack2(float a, float b) {
  return (unsigned)f2bf(a) | ((unsigned)f2bf(b) << 16);
}

#define MFMA16(a, b, c) __builtin_amdgcn_mfma_f32_16x16x32_bf16(a, b, c, 0, 0, 0)

// ============================================================================
// wprepT: [O][C][T] f32 -> [tap][O][C] bf16 via LDS tile transpose.
// ============================================================================
__global__ __launch_bounds__(256) void wprepT_kernel(
    const float* c1w, const float* c2w, const float* c3w, const float* c4w,
    const float* c5w, const float* lw0, const float* lw1, const float* lw2,
    unsigned short* wb1, unsigned short* wb2, unsigned short* wb3,
    unsigned short* wb4, unsigned short* wb5, unsigned short* wbf0,
    unsigned short* wbf1, unsigned short* wbf2)
{
  __shared__ float lds[256 * 26];
  const int tid = threadIdx.x;
  int b = blockIdx.x;

  const float* src;
  unsigned short* dst;
  int T, OC, base;
  if (b < 8)         { src = c2w; dst = wb2;  T = 16; OC = 2048;   base = b * 256; }
  else if (b < 40)   { src = c3w; dst = wb3;  T = 16; OC = 8192;   base = (b - 8) * 256; }
  else if (b < 168)  { src = c4w; dst = wb4;  T = 16; OC = 32768;  base = (b - 40) * 256; }
  else if (b < 680)  { src = c5w; dst = wb5;  T = 16; OC = 131072; base = (b - 168) * 256; }
  else if (b < 872)  { src = lw1; dst = wbf1; T = 25; OC = 49152;  base = (b - 680) * 256; }
  else if (b < 1000) { src = lw2; dst = wbf2; T = 25; OC = 32768;  base = (b - 872) * 256; }
  else if (b < 2280) { src = lw0; dst = wbf0; T = 25; OC = 327680; base = (b - 1000) * 256; }
  else {
    int i = (b - 2280) * 256 + tid;   // 16384 total
    int o = i >> 9, c = i & 511;
    wb1[(((c >> 5) * 32) + o) * 32 + (c & 31)] = f2bf(c1w[i]);
    return;
  }

  const float* sp = src + (size_t)base * T;
  for (int e = tid; e < 256 * T; e += 256) {
    int oc = e / T, tap = e - oc * T;
    lds[oc * 26 + tap] = sp[e];
  }
  __syncthreads();
  for (int tap = 0; tap < T; ++tap)
    dst[(size_t)tap * OC + base + tid] = f2bf(lds[tid * 26 + tap]);
}

// ============================================================================
// conv1M: 1x1 conv 512->32 as MFMA GEMM (R17 bank-derived staging).
// ============================================================================
__global__ __launch_bounds__(256) void conv1M_kernel(
    const float* __restrict__ h, const unsigned short* __restrict__ wbc,
    float* __restrict__ xT, float* __restrict__ part1)
{
  __shared__ __align__(16) unsigned short inT[256 * 40];   // 20 KB, [px][ch(+pad)]
  __shared__ float red1[4][4][2][4][2];

  const int n = blockIdx.y, r = blockIdx.x;   // r = output row 0..255
  const int px0 = r * 256;
  const int tid = threadIdx.x, lane = tid & 63, wid = tid >> 6;
  const int ln15 = lane & 15, kg = lane >> 4;
  const bool rint = (r >= 1 && r <= 254);     // block-uniform

  f32x4 acc[2][4];
#pragma unroll
  for (int m = 0; m < 2; ++m)
#pragma unroll
    for (int f = 0; f < 4; ++f) acc[m][f] = (f32x4){0.f, 0.f, 0.f, 0.f};

  float rv0[4][4], rv1[4][4];

#define LOADR(KC)                                                                \
  {                                                                              \
    _Pragma("unroll")                                                            \
    for (int k = 0; k < 4; ++k) {                                                \
      const int u = tid + k * 256;                                               \
      const int chp = u >> 6;                                                    \
      const int pxb = u & 63;                                                    \
      const int ch = 2 * chp;                                                    \
      const float* hrow0 = h + ((size_t)(n * 512 + (KC) * 32 + ch)) * 64516      \
                             + (size_t)(r - 1) * 254;                            \
      const float* hrow1 = hrow0 + 64516;                                        \
      _Pragma("unroll")                                                          \
      for (int j = 0; j < 4; ++j) {                                              \
        const int px = pxb + 64 * j;                                             \
        const bool ok = rint && (px >= 1) && (px <= 254);                        \
        rv0[k][j] = ok ? hrow0[px - 1] : 0.f;                                    \
        rv1[k][j] = ok ? hrow1[px - 1] : 0.f;                                    \
      }                                                                          \
    }                                                                            \
  }

#define WRITELDS()                                                               \
  {                                                                              \
    _Pragma("unroll")                                                            \
    for (int k = 0; k < 4; ++k) {                                                \
      const int u = tid + k * 256;                                               \
      const int chp = u >> 6;                                                    \
      const int pxb = u & 63;                                                    \
      _Pragma("unroll")                                                          \
      for (int j = 0; j < 4; ++j) {                                              \
        const int px = pxb + 64 * j;                                             \
        *(unsigned*)&inT[px * 40 + 2 * chp] = pack2(rv0[k][j], rv1[k][j]);       \
      }                                                                          \
    }                                                                            \
  }

  LOADR(0);
  for (int kc = 0; kc < 16; ++kc) {
    __syncthreads();
    WRITELDS();
    __syncthreads();
    if (kc < 15) LOADR(kc + 1);

    const bf16x8 a0 = *(const bf16x8*)(wbc + ((size_t)(kc * 32 + ln15)) * 32 + kg * 8);
    const bf16x8 a1 = *(const bf16x8*)(wbc + ((size_t)(kc * 32 + 16 + ln15)) * 32 + kg * 8);
#pragma unroll
    for (int f = 0; f < 4; ++f) {
      const int pxr = wid * 64 + f * 16 + ln15;
      const bf16x8 b = *(const bf16x8*)&inT[pxr * 40 + kg * 8];
      acc[0][f] = MFMA16(a0, b, acc[0][f]);
      acc[1][f] = MFMA16(a1, b, acc[1][f]);
    }
  }
#undef LOADR
#undef WRITELDS

#pragma unroll
  for (int mf = 0; mf < 2; ++mf) {
#pragma unroll
    for (int f = 0; f < 4; ++f) {
      const int px = px0 + wid * 64 + f * 16 + ln15;
      const int o = mf * 16 + kg * 4;
      *(f32x4*)(xT + ((size_t)n * 65536 + px) * 32 + o) = acc[mf][f];
    }
  }

#pragma unroll
  for (int mf = 0; mf < 2; ++mf) {
#pragma unroll
    for (int j = 0; j < 4; ++j) {
      float s = 0.f, q = 0.f;
#pragma unroll
      for (int f = 0; f < 4; ++f) { float v = acc[mf][f][j]; s += v; q += v * v; }
#pragma unroll
      for (int mk = 1; mk < 16; mk <<= 1) {
        s += __shfl_xor(s, mk);
        q += __shfl_xor(q, mk);
      }
      if (ln15 == 0) { red1[wid][kg][mf][j][0] = s; red1[wid][kg][mf][j][1] = q; }
    }
  }
  __syncthreads();
  if (tid < 32) {
    const int mf = tid >> 4, kgi = (tid >> 2) & 3, j = tid & 3;
    float s = red1[0][kgi][mf][j][0] + red1[1][kgi][mf][j][0]
            + red1[2][kgi][mf][j][0] + red1[3][kgi][mf][j][0];
    float q = red1[0][kgi][mf][j][1] + red1[1][kgi][mf][j][1]
            + red1[2][kgi][mf][j][1] + red1[3][kgi][mf][j][1];
    atomicAdd(&part1[tid], s);
    atomicAdd(&part1[32 + tid], q);
  }
}

// ============================================================================
// cbn1T: inline stats; normalize + lrelu; write padded bf16 T2.
// ============================================================================
__global__ __launch_bounds__(256) void cbn1T_kernel(
    const float* __restrict__ xT, const float* __restrict__ part1, float invN,
    const float* __restrict__ e1, const int* __restrict__ objs,
    unsigned short* __restrict__ T2)
{
  __shared__ float st[32][4];
  const int n = blockIdx.y;
  if (threadIdx.x < 32) {
    int y = objs[n];
    float s = part1[threadIdx.x], q = part1[32 + threadIdx.x];
    float mean = s * invN;
    st[threadIdx.x][0] = mean;
    st[threadIdx.x][1] = rsqrtf(q * invN - mean * mean + 1e-5f);
    st[threadIdx.x][2] = e1[(size_t)y * 64 + threadIdx.x];
    st[threadIdx.x][3] = e1[(size_t)y * 64 + 32 + threadIdx.x];
  }
  __syncthreads();
  const int pix = blockIdx.x * 256 + threadIdx.x;
  const int r = pix >> 8, c = pix & 255;
  const float* src = xT + ((size_t)n * 65536 + pix) * 32;
  unsigned short* dst = T2 + ((size_t)n * 66564 + (size_t)(r + 1) * 258 + (c + 1)) * 32;
  unsigned outw[16];
#pragma unroll
  for (int q = 0; q < 8; ++q) {
    float4 t = ((const float4*)src)[q];
    float v[4] = {t.x, t.y, t.z, t.w};
#pragma unroll
    for (int j = 0; j < 4; ++j) {
      int ch = q * 4 + j;
      float z = (v[j] - st[ch][0]) * st[ch][1] * st[ch][2] + st[ch][3];
      v[j] = z >= 0.f ? z : LEAK * z;
    }
    outw[2 * q]     = pack2(v[0], v[1]);
    outw[2 * q + 1] = pack2(v[2], v[3]);
  }
  uint4* d4 = (uint4*)dst;
#pragma unroll
  for (int q = 0; q < 4; ++q)
    d4[q] = make_uint4(outw[4*q], outw[4*q+1], outw[4*q+2], outw[4*q+3]);
}

// ============================================================================
// conv4T: 4x4 s2 p1 conv, stage-free. WM template.
// ============================================================================
template <int C, int O, int H, int WM>
__global__ __launch_bounds__(256) void conv4T_kernel(
    const unsigned short* __restrict__ Tin, const unsigned short* __restrict__ wb,
    float* __restrict__ raw, float* __restrict__ part)
{
  constexpr int HIN2 = 2 * H + 2;
  constexpr int KC = C / 32;
  constexpr int WN4 = 4 / WM;
  constexpr int NT = WM;
  constexpr int LOGH = (H == 128 ? 7 : (H == 64 ? 6 : (H == 32 ? 5 : 4)));
  __shared__ float red[4][4][2][4][2];
  const int o0 = blockIdx.x * (WM * 32);
  const int strip = blockIdx.y;
  const int n = blockIdx.z;
  const int tid = threadIdx.x, lane = tid & 63, wid = tid >> 6;
  const int wm = wid / WN4, wn = wid % WN4;
  const int ln15 = lane & 15, kg = lane >> 4;
  const unsigned short* inb = Tin + (size_t)n * (HIN2 * HIN2) * C;

  f32x4 acc[2][NT];
#pragma unroll
  for (int m = 0; m < 2; ++m)
#pragma unroll
    for (int nt = 0; nt < NT; ++nt) acc[m][nt] = (f32x4){0.f, 0.f, 0.f, 0.f};

  int r_[NT], c_[NT];
#pragma unroll
  for (int nt = 0; nt < NT; ++nt) {
    const int gp = strip * 64 + (wn * NT + nt) * 16;
    r_[nt] = gp >> LOGH;
    c_[nt] = (gp & (H - 1)) + ln15;
  }

  for (int kc = 0; kc < KC; ++kc) {
    const int cb = kc * 32 + kg * 8;
#pragma unroll
    for (int tap = 0; tap < 16; ++tap) {
      const int ky = tap >> 2, kx = tap & 3;
      const unsigned short* ap = wb + ((size_t)tap * O + o0 + wm * 32 + ln15) * C + cb;
      bf16x8 a0 = *(const bf16x8*)ap;
      bf16x8 a1 = *(const bf16x8*)(ap + (size_t)16 * C);
#pragma unroll
      for (int nt = 0; nt < NT; ++nt) {
        bf16x8 b = *(const bf16x8*)(inb + (size_t)((2 * r_[nt] + ky) * HIN2 + 2 * c_[nt] + kx) * C + cb);
        acc[0][nt] = MFMA16(a0, b, acc[0][nt]);
        acc[1][nt] = MFMA16(a1, b, acc[1][nt]);
      }
    }
  }

#pragma unroll
  for (int mf = 0; mf < 2; ++mf) {
    const int o = o0 + wm * 32 + mf * 16 + kg * 4;
#pragma unroll
    for (int nt = 0; nt < NT; ++nt) {
      const int gp = strip * 64 + (wn * NT + nt) * 16 + ln15;
      *(f32x4*)(raw + ((size_t)n * (H * H) + gp) * O + o) = acc[mf][nt];
    }
  }

#pragma unroll
  for (int mf = 0; mf < 2; ++mf) {
#pragma unroll
    for (int j = 0; j < 4; ++j) {
      float s = 0.f, q = 0.f;
#pragma unroll
      for (int nt = 0; nt < NT; ++nt) { float v = acc[mf][nt][j]; s += v; q += v * v; }
#pragma unroll
      for (int mk = 1; mk < 16; mk <<= 1) {
        s += __shfl_xor(s, mk);
        q += __shfl_xor(q, mk);
      }
      if (ln15 == 0) { red[wid][kg][mf][j][0] = s; red[wid][kg][mf][j][1] = q; }
    }
  }
  __syncthreads();
  if (tid < WM * 32) {
    const int wmi = tid >> 5, mf = (tid >> 4) & 1, kgi = (tid >> 2) & 3, j = tid & 3;
    float s = 0.f, q = 0.f;
#pragma unroll
    for (int w = 0; w < WN4; ++w) {
      s += red[wmi * WN4 + w][kgi][mf][j][0];
      q += red[wmi * WN4 + w][kgi][mf][j][1];
    }
    atomicAdd(&part[o0 + tid], s);
    atomicAdd(&part[O + o0 + tid], q);
  }
}

// ============================================================================
// cbnT: inline stats; normalize (+lrelu); write padded bf16.
// ============================================================================
template <int C, int H, int P2, int CSO, bool LRELU, bool LMAP>
__global__ __launch_bounds__(256) void cbnT_kernel(
    const float* __restrict__ raw, const float* __restrict__ part, float invN,
    const float* __restrict__ embed, const int* __restrict__ objs,
    unsigned short* __restrict__ Tout)
{
  constexpr int W2 = H + 2 * P2;
  constexpr int LOGH = (H == 128 ? 7 : (H == 64 ? 6 : (H == 32 ? 5 : 4)));
  const int n = blockIdx.y;
  const int y = objs[n];
  const int pix = blockIdx.x * 64 + (threadIdx.x >> 2);
  const int r = pix >> LOGH, c = pix & (H - 1);
  const float* src = raw + ((size_t)n * (H * H) + pix) * C;
  const size_t nb = LMAP ? (size_t)((n & 1) * 4 + (n >> 1)) * (W2 * W2) * CSO
                         : (size_t)n * (W2 * W2) * CSO;
  unsigned short* dst = Tout + nb + ((size_t)(r + P2) * W2 + c + P2) * CSO;
  const float* gam = embed + (size_t)y * 2 * C;
  const float* bet = gam + C;
  for (int cs = (threadIdx.x & 3); cs < C / 8; cs += 4) {
    float4 ps0 = ((const float4*)part)[cs * 2],       ps1 = ((const float4*)part)[cs * 2 + 1];
    float4 pq0 = ((const float4*)(part + C))[cs * 2], pq1 = ((const float4*)(part + C))[cs * 2 + 1];
    float4 g0 = ((const float4*)gam)[cs * 2], g1 = ((const float4*)gam)[cs * 2 + 1];
    float4 b0 = ((const float4*)bet)[cs * 2], b1 = ((const float4*)bet)[cs * 2 + 1];
    float4 v0 = ((const float4*)src)[cs * 2], v1 = ((const float4*)src)[cs * 2 + 1];
    float sv[8] = {ps0.x, ps0.y, ps0.z, ps0.w, ps1.x, ps1.y, ps1.z, ps1.w};
    float qv[8] = {pq0.x, pq0.y, pq0.z, pq0.w, pq1.x, pq1.y, pq1.z, pq1.w};
    float gv[8] = {g0.x, g0.y, g0.z, g0.w, g1.x, g1.y, g1.z, g1.w};
    float bv[8] = {b0.x, b0.y, b0.z, b0.w, b1.x, b1.y, b1.z, b1.w};
    float vv[8] = {v0.x, v0.y, v0.z, v0.w, v1.x, v1.y, v1.z, v1.w};
    float o_[8];
#pragma unroll
    for (int k = 0; k < 8; ++k) {
      float m = sv[k] * invN;
      float rs = rsqrtf(qv[k] * invN - m * m + 1e-5f);
      float z = (vv[k] - m) * rs * gv[k] + bv[k];
      o_[k] = (LRELU && z < 0.f) ? LEAK * z : z;
    }
    ((uint4*)dst)[cs] = make_uint4(pack2(o_[0], o_[1]), pack2(o_[2], o_[3]),
                                   pack2(o_[4], o_[5]), pack2(o_[6], o_[7]));
  }
}

// ============================================================================
// conv5L: 5x5 s1 p2 conv on 16x16 (ConvLSTM), stage-free, 1 chunk/block.
// ============================================================================
template <int O, int CS, int WM, int WN>
__global__ __launch_bounds__(256) void conv5L_kernel(
    const unsigned short* __restrict__ Lin, const unsigned short* __restrict__ wbf,
    float* __restrict__ pp, int kbeg, int slot0, size_t lin_tstr, size_t pp_tstr)
{
  constexpr int FN = 16 / WN;
  const int o0 = blockIdx.x * (WM * 32);
  const int b = blockIdx.y & 3, t = blockIdx.y >> 2;
  const int ks = blockIdx.z;
  const int tid = threadIdx.x, lane = tid & 63, wid = tid >> 6;
  const int wm = wid / WN, wn = wid % WN;
  const int ln15 = lane & 15, kg = lane >> 4;
  const unsigned short* inb = Lin + (size_t)t * lin_tstr + (size_t)b * 400 * CS;
  float* ppb = pp + (size_t)t * pp_tstr + ((size_t)(slot0 + ks) * 4 + b) * (256 * O);

  f32x4 acc[2][FN];
#pragma unroll
  for (int m = 0; m < 2; ++m)
#pragma unroll
    for (int nt = 0; nt < FN; ++nt) acc[m][nt] = (f32x4){0.f, 0.f, 0.f, 0.f};

  const int cb = (kbeg + ks) * 32 + kg * 8;
  for (int tap = 0; tap < 25; ++tap) {
    const int ty = tap / 5, tx = tap - 5 * ty;
    const unsigned short* ap = wbf + ((size_t)tap * O + o0 + wm * 32 + ln15) * CS + cb;
    bf16x8 a0 = *(const bf16x8*)ap;
    bf16x8 a1 = *(const bf16x8*)(ap + (size_t)16 * CS);
#pragma unroll
    for (int nt = 0; nt < FN; ++nt) {
      const int p = (wn * FN + nt) * 16 + ln15;
      const int prow = p >> 4, pcol = p & 15;
      bf16x8 bfv = *(const bf16x8*)(inb + (size_t)((prow + ty) * 20 + pcol + tx) * CS + cb);
      acc[0][nt] = MFMA16(a0, bfv, acc[0][nt]);
      acc[1][nt] = MFMA16(a1, bfv, acc[1][nt]);
    }
  }

#pragma unroll
  for (int mf = 0; mf < 2; ++mf) {
    const int o = o0 + wm * 32 + mf * 16 + kg * 4;
#pragma unroll
    for (int nt = 0; nt < FN; ++nt) {
      const int pix = (wn * FN + nt) * 16 + ln15;
      *(f32x4*)(ppb + (size_t)pix * O + o) = acc[mf][nt];
    }
  }
}

// ============================================================================
// lstm_pointT: sum KS pp-slots, gates -> (c,h).
// ============================================================================
template <int Hc, int CS, int CX, int CSN>
__global__ __launch_bounds__(256) void lstm_pointT_kernel(
    const float* __restrict__ pp, int KS, const float* __restrict__ bias,
    float* __restrict__ cT, unsigned short* __restrict__ own,
    unsigned short* __restrict__ nxt, float* __restrict__ fout)
{
  constexpr int C4 = Hc / 4;
  constexpr int O = 4 * Hc;
  constexpr int LOGC4 = (C4 == 32 ? 5 : 4);
  const int i = blockIdx.x * 256 + threadIdx.x;
  const int c4 = i & (C4 - 1);
  const int pix = (i >> LOGC4) & 255;
  const int b = i >> (LOGC4 + 8);

  float g[4][4];
#pragma unroll
  for (int gt = 0; gt < 4; ++gt)
#pragma unroll
    for (int j = 0; j < 4; ++j) g[gt][j] = 0.f;

  for (int ks = 0; ks < KS; ++ks) {
    const float* base = pp + (((size_t)(ks * 4 + b)) * 256 + pix) * O + c4 * 4;
#pragma unroll
    for (int gt = 0; gt < 4; ++gt) {
      float4 v = *(const float4*)(base + gt * Hc);
      g[gt][0] += v.x; g[gt][1] += v.y; g[gt][2] += v.z; g[gt][3] += v.w;
    }
  }
#pragma unroll
  for (int gt = 0; gt < 4; ++gt) {
    float4 bv = *(const float4*)(bias + gt * Hc + c4 * 4);
    g[gt][0] += bv.x; g[gt][1] += bv.y; g[gt][2] += bv.z; g[gt][3] += bv.w;
  }

  float* cp = cT + ((size_t)b * 256 + pix) * Hc + c4 * 4;
  float4 cold = *(const float4*)cp;
  float co[4] = {cold.x, cold.y, cold.z, cold.w};
  float hn[4];
#pragma unroll
  for (int j = 0; j < 4; ++j) {
    float si = 1.f / (1.f + expf(-g[0][j]));
    float sf = 1.f / (1.f + expf(-g[1][j]));
    float so = 1.f / (1.f + expf(-g[2][j]));
    float cn = sf * co[j] + si * tanhf(g[3][j]);
    co[j] = cn;
    hn[j] = so * tanhf(cn);
  }
  *(float4*)cp = make_float4(co[0], co[1], co[2], co[3]);

  const int prow = pix >> 4, pcol = pix & 15;
  const int ppix = (prow + 2) * 20 + pcol + 2;
  uint2 hb = make_uint2(pack2(hn[0], hn[1]), pack2(hn[2], hn[3]));
  if (own) *(uint2*)(own + ((size_t)b * 400 + ppix) * CS + CX + c4 * 4) = hb;
  if (nxt) *(uint2*)(nxt + ((size_t)b * 400 + ppix) * CSN + c4 * 4) = hb;
  if (fout) {
#pragma unroll
    for (int j = 0; j < 4; ++j)
      fout[((size_t)b * Hc + c4 * 4 + j) * 256 + pix] = hn[j];
  }
}

// ============================================================================
extern "C" void kernel_launch(void* const* d_in, const int* in_sizes, int n_in,
                              void* d_out, int out_size, void* d_ws, size_t ws_size,
                              hipStream_t stream)
{
  const float* h    = (const float*)d_in[0];
  const int*   objs = (const int*)  d_in[1];
  const float* c1w  = (const float*)d_in[3];
  const float* c2w  = (const float*)d_in[4];
  const float* c3w  = (const float*)d_in[5];
  const float* c4w  = (const float*)d_in[6];
  const float* c5w  = (const float*)d_in[7];
  const float* e1   = (const float*)d_in[8];
  const float* e2   = (const float*)d_in[9];
  const float* e3   = (const float*)d_in[10];
  const float* e4   = (const float*)d_in[11];
  const float* e5   = (const float*)d_in[12];
  const float* lw0  = (const float*)d_in[13];
  const float* lb0  = (const float*)d_in[14];
  const float* lw1  = (const float*)d_in[15];
  const float* lb1  = (const float*)d_in[16];
  const float* lw2  = (const float*)d_in[17];
  const float* lb2  = (const float*)d_in[18];

  char* p = (char*)d_ws;
  auto alloc = [&](size_t bytes) { char* r = p; p += (bytes + 255) & ~(size_t)255; return r; };
  // ---- non-zeroed ----
  float* x1T  = (float*)alloc((size_t)8 * 65536 * 32 * 4);
  float* raw2 = (float*)alloc((size_t)8 * 16384 * 64 * 4);
  float* raw3 = (float*)alloc((size_t)8 * 4096 * 128 * 4);
  float* raw4 = (float*)alloc((size_t)8 * 1024 * 256 * 4);
  float* raw5 = (float*)alloc((size_t)8 * 256 * 512 * 4);
  float* pp   = (float*)alloc((size_t)2 * 20 * 4 * 256 * 512 * 4);   // 84 MB
  unsigned short* wb1  = (unsigned short*)alloc((size_t)32 * 512 * 2);
  unsigned short* wb2  = (unsigned short*)alloc((size_t)16 * 64 * 32 * 2);
  unsigned short* wb3  = (unsigned short*)alloc((size_t)16 * 128 * 64 * 2);
  unsigned short* wb4  = (unsigned short*)alloc((size_t)16 * 256 * 128 * 2);
  unsigned short* wb5  = (unsigned short*)alloc((size_t)16 * 512 * 256 * 2);
  unsigned short* wbf0 = (unsigned short*)alloc((size_t)25 * 512 * 640 * 2);
  unsigned short* wbf1 = (unsigned short*)alloc((size_t)25 * 256 * 192 * 2);
  unsigned short* wbf2 = (unsigned short*)alloc((size_t)25 * 256 * 128 * 2);
  // ---- contiguous ZERO region (single memset) ----
  char* zbase = p;
  unsigned short* T2 = (unsigned short*)alloc((size_t)8 * 66564 * 32 * 2);
  unsigned short* T3 = (unsigned short*)alloc((size_t)8 * 16900 * 64 * 2);
  unsigned short* T4 = (unsigned short*)alloc((size_t)8 * 4356 * 128 * 2);
  unsigned short* T5 = (unsigned short*)alloc((size_t)8 * 1156 * 256 * 2);
  unsigned short* L0in = (unsigned short*)alloc((size_t)2 * 4 * 400 * 640 * 2);
  unsigned short* L1in = (unsigned short*)alloc((size_t)2 * 4 * 400 * 192 * 2);
  unsigned short* L2in = (unsigned short*)alloc((size_t)2 * 4 * 400 * 128 * 2);
  float* cT0 = (float*)alloc((size_t)4 * 256 * 128 * 4);
  float* cT1 = (float*)alloc((size_t)4 * 256 * 64 * 4);
  float* cT2 = (float*)alloc((size_t)4 * 256 * 64 * 4);
  float* part1 = (float*)alloc(2 * 32 * 4);
  char* pz2 = p;                                   // start of part2..part5
  float* part2 = (float*)alloc(2 * 64 * 4);
  float* part3 = (float*)alloc(2 * 128 * 4);
  float* part4 = (float*)alloc(2 * 256 * 4);
  float* part5 = (float*)alloc(2 * 512 * 4);
  size_t pzsize = (size_t)(p - pz2);
  size_t zsize = (size_t)(p - zbase);

  hipMemsetAsync(zbase, 0, zsize, stream);
  wprepT_kernel<<<2344, 256, 0, stream>>>(
      c1w, c2w, c3w, c4w, c5w, lw0, lw1, lw2,
      wb1, wb2, wb3, wb4, wb5, wbf0, wbf1, wbf2);

  // ---- stage 1 ----
  conv1M_kernel<<<dim3(256, 8), 256, 0, stream>>>(h, wb1, x1T, part1);
  cbn1T_kernel<<<dim3(256, 8), 256, 0, stream>>>(x1T, part1, 1.f / (float)(8 * 65536), e1, objs, T2);

  // ---- stages 2-5 (pass A) ----
  conv4T_kernel<32, 64, 128, 2><<<dim3(1, 256, 8), 256, 0, stream>>>(T2, wb2, raw2, part2);
  cbnT_kernel<64, 128, 1, 64, true, false><<<dim3(256, 8), 256, 0, stream>>>(
      raw2, part2, 1.f / (float)(8 * 16384), e2, objs, T3);
  conv4T_kernel<64, 128, 64, 2><<<dim3(2, 64, 8), 256, 0, stream>>>(T3, wb3, raw3, part3);
  cbnT_kernel<128, 64, 1, 128, true, false><<<dim3(64, 8), 256, 0, stream>>>(
      raw3, part3, 1.f / (float)(8 * 4096), e3, objs, T4);
  conv4T_kernel<128, 256, 32, 1><<<dim3(8, 16, 8), 256, 0, stream>>>(T4, wb4, raw4, part4);
  cbnT_kernel<256, 32, 1, 256, false, false><<<dim3(16, 8), 256, 0, stream>>>(
      raw4, part4, 1.f / (float)(8 * 1024), e4, objs, T5);
  conv4T_kernel<256, 512, 16, 1><<<dim3(16, 4, 8), 256, 0, stream>>>(T5, wb5, raw5, part5);
  cbnT_kernel<512, 16, 2, 640, false, true><<<dim3(4, 8), 256, 0, stream>>>(
      raw5, part5, 1.f / (float)(8 * 256), e5, objs, L0in);

  // ---- TELEMETRY (R18): duplicate stages 2-5. Zero part2..part5 (atomics),
  // then re-run all 8 stage kernels with identical inputs -> identical final
  // state. dur delta vs R17 == full cost of the stages-2-5 region.
  hipMemsetAsync(pz2, 0, pzsize, stream);
  conv4T_kernel<32, 64, 128, 2><<<dim3(1, 256, 8), 256, 0, stream>>>(T2, wb2, raw2, part2);
  cbnT_kernel<64, 128, 1, 64, true, false><<<dim3(256, 8), 256, 0, stream>>>(
      raw2, part2, 1.f / (float)(8 * 16384), e2, objs, T3);
  conv4T_kernel<64, 128, 64, 2><<<dim3(2, 64, 8), 256, 0, stream>>>(T3, wb3, raw3, part3);
  cbnT_kernel<128, 64, 1, 128, true, false><<<dim3(64, 8), 256, 0, stream>>>(
      raw3, part3, 1.f / (float)(8 * 4096), e3, objs, T4);
  conv4T_kernel<128, 256, 32, 1><<<dim3(8, 16, 8), 256, 0, stream>>>(T4, wb4, raw4, part4);
  cbnT_kernel<256, 32, 1, 256, false, false><<<dim3(16, 8), 256, 0, stream>>>(
      raw4, part4, 1.f / (float)(8 * 1024), e4, objs, T5);
  conv4T_kernel<256, 512, 16, 1><<<dim3(16, 4, 8), 256, 0, stream>>>(T5, wb5, raw5, part5);
  cbnT_kernel<512, 16, 2, 640, false, true><<<dim3(4, 8), 256, 0, stream>>>(
      raw5, part5, 1.f / (float)(8 * 256), e5, objs, L0in);

  // ---- ConvLSTM 0 (C=640: x=16 chunks, h=4 chunks) ----
  {
    const size_t LINT = (size_t)4 * 400 * 640;
    const size_t PPT  = (size_t)20 * 4 * 256 * 512;
    conv5L_kernel<512, 640, 2, 2><<<dim3(8, 8, 16), 256, 0, stream>>>(
        L0in, wbf0, pp, 0, 0, LINT, PPT);
    lstm_pointT_kernel<128, 640, 512, 192><<<128, 256, 0, stream>>>(
        pp, 16, lb0, cT0, L0in + LINT, L1in, nullptr);
    conv5L_kernel<512, 640, 2, 2><<<dim3(8, 4, 4), 256, 0, stream>>>(
        L0in + LINT, wbf0, pp + PPT, 16, 16, 0, 0);
    lstm_pointT_kernel<128, 640, 512, 192><<<128, 256, 0, stream>>>(
        pp + PPT, 20, lb0, cT0, nullptr, L1in + (size_t)4 * 400 * 192, nullptr);
  }

  // ---- ConvLSTM 1 (C=192: x=4, h=2) ----
  {
    const size_t LINT = (size_t)4 * 400 * 192;
    const size_t PPT  = (size_t)6 * 4 * 256 * 256;
    conv5L_kernel<256, 192, 1, 4><<<dim3(8, 8, 4), 256, 0, stream>>>(
        L1in, wbf1, pp, 0, 0, LINT, PPT);
    lstm_pointT_kernel<64, 192, 128, 128><<<64, 256, 0, stream>>>(
        pp, 4, lb1, cT1, L1in + LINT, L2in, nullptr);
    conv5L_kernel<256, 192, 1, 4><<<dim3(8, 4, 2), 256, 0, stream>>>(
        L1in + LINT, wbf1, pp + PPT, 4, 4, 0, 0);
    lstm_pointT_kernel<64, 192, 128, 128><<<64, 256, 0, stream>>>(
        pp + PPT, 6, lb1, cT1, nullptr, L2in + (size_t)4 * 400 * 128, nullptr);
  }

  // ---- ConvLSTM 2 (C=128: x=2, h=2), final h -> d_out ----
  {
    const size_t LINT = (size_t)4 * 400 * 128;
    const size_t PPT  = (size_t)4 * 4 * 256 * 256;
    conv5L_kernel<256, 128, 1, 4><<<dim3(8, 8, 2), 256, 0, stream>>>(
        L2in, wbf2, pp, 0, 0, LINT, PPT);
    lstm_pointT_kernel<64, 128, 64, 1><<<64, 256, 0, stream>>>(
        pp, 2, lb2, cT2, L2in + LINT, nullptr, nullptr);
    conv5L_kernel<256, 128, 1, 4><<<dim3(8, 4, 2), 256, 0, stream>>>(
        L2in + LINT, wbf2, pp + PPT, 2, 2, 0, 0);
    lstm_pointT_kernel<64, 128, 64, 1><<<64, 256, 0, stream>>>(
        pp + PPT, 4, lb2, cT2, nullptr, nullptr, (float*)d_out);
  }
}

// Round 19
// 911.361 us; speedup vs baseline: 1.4574x; 1.4574x over previous
//
#include <hip/hip_runtime.h>
#include <math.h>

#define LEAK 0.2f

typedef __attribute__((ext_vector_type(8))) short bf16x8;
typedef __attribute__((ext_vector_type(4))) float f32x4;

__device__ __forceinline__ unsigned short f2bf(float f) {
  unsigned u = __float_as_uint(f);
  u += 0x7FFFu + ((u >> 16) & 1u);
  return (unsigned short)(u >> 16);
}
__device__ __forceinline__ unsigned pack2(float a, float b) {
  return (unsigned)f2bf(a) | ((unsigned)f2bf(b) << 16);
}

#define MFMA16(a, b, c) __builtin_amdgcn_mfma_f32_16x16x32_bf16(a, b, c, 0, 0, 0)

// ============================================================================
// wprepT: [O][C][T] f32 -> [tap][O][C] bf16 via LDS tile transpose.
// ============================================================================
__global__ __launch_bounds__(256) void wprepT_kernel(
    const float* c1w, const float* c2w, const float* c3w, const float* c4w,
    const float* c5w, const float* lw0, const float* lw1, const float* lw2,
    unsigned short* wb1, unsigned short* wb2, unsigned short* wb3,
    unsigned short* wb4, unsigned short* wb5, unsigned short* wbf0,
    unsigned short* wbf1, unsigned short* wbf2)
{
  __shared__ float lds[256 * 26];
  const int tid = threadIdx.x;
  int b = blockIdx.x;

  const float* src;
  unsigned short* dst;
  int T, OC, base;
  if (b < 8)         { src = c2w; dst = wb2;  T = 16; OC = 2048;   base = b * 256; }
  else if (b < 40)   { src = c3w; dst = wb3;  T = 16; OC = 8192;   base = (b - 8) * 256; }
  else if (b < 168)  { src = c4w; dst = wb4;  T = 16; OC = 32768;  base = (b - 40) * 256; }
  else if (b < 680)  { src = c5w; dst = wb5;  T = 16; OC = 131072; base = (b - 168) * 256; }
  else if (b < 872)  { src = lw1; dst = wbf1; T = 25; OC = 49152;  base = (b - 680) * 256; }
  else if (b < 1000) { src = lw2; dst = wbf2; T = 25; OC = 32768;  base = (b - 872) * 256; }
  else if (b < 2280) { src = lw0; dst = wbf0; T = 25; OC = 327680; base = (b - 1000) * 256; }
  else {
    int i = (b - 2280) * 256 + tid;   // 16384 total
    int o = i >> 9, c = i & 511;
    wb1[(((c >> 5) * 32) + o) * 32 + (c & 31)] = f2bf(c1w[i]);
    return;
  }

  const float* sp = src + (size_t)base * T;
  for (int e = tid; e < 256 * T; e += 256) {
    int oc = e / T, tap = e - oc * T;
    lds[oc * 26 + tap] = sp[e];
  }
  __syncthreads();
  for (int tap = 0; tap < T; ++tap)
    dst[(size_t)tap * OC + base + tid] = f2bf(lds[tid * 26 + tap]);
}

// ============================================================================
// conv1M: 1x1 conv 512->32 as MFMA GEMM (R17 bank-derived staging).
// ============================================================================
__global__ __launch_bounds__(256) void conv1M_kernel(
    const float* __restrict__ h, const unsigned short* __restrict__ wbc,
    float* __restrict__ xT, float* __restrict__ part1)
{
  __shared__ __align__(16) unsigned short inT[256 * 40];   // 20 KB, [px][ch(+pad)]
  __shared__ float red1[4][4][2][4][2];

  const int n = blockIdx.y, r = blockIdx.x;   // r = output row 0..255
  const int px0 = r * 256;
  const int tid = threadIdx.x, lane = tid & 63, wid = tid >> 6;
  const int ln15 = lane & 15, kg = lane >> 4;
  const bool rint = (r >= 1 && r <= 254);     // block-uniform

  f32x4 acc[2][4];
#pragma unroll
  for (int m = 0; m < 2; ++m)
#pragma unroll
    for (int f = 0; f < 4; ++f) acc[m][f] = (f32x4){0.f, 0.f, 0.f, 0.f};

  float rv0[4][4], rv1[4][4];

#define LOADR(KC)                                                                \
  {                                                                              \
    _Pragma("unroll")                                                            \
    for (int k = 0; k < 4; ++k) {                                                \
      const int u = tid + k * 256;                                               \
      const int chp = u >> 6;                                                    \
      const int pxb = u & 63;                                                    \
      const int ch = 2 * chp;                                                    \
      const float* hrow0 = h + ((size_t)(n * 512 + (KC) * 32 + ch)) * 64516      \
                             + (size_t)(r - 1) * 254;                            \
      const float* hrow1 = hrow0 + 64516;                                        \
      _Pragma("unroll")                                                          \
      for (int j = 0; j < 4; ++j) {                                              \
        const int px = pxb + 64 * j;                                             \
        const bool ok = rint && (px >= 1) && (px <= 254);                        \
        rv0[k][j] = ok ? hrow0[px - 1] : 0.f;                                    \
        rv1[k][j] = ok ? hrow1[px - 1] : 0.f;                                    \
      }                                                                          \
    }                                                                            \
  }

#define WRITELDS()                                                               \
  {                                                                              \
    _Pragma("unroll")                                                            \
    for (int k = 0; k < 4; ++k) {                                                \
      const int u = tid + k * 256;                                               \
      const int chp = u >> 6;                                                    \
      const int pxb = u & 63;                                                    \
      _Pragma("unroll")                                                          \
      for (int j = 0; j < 4; ++j) {                                              \
        const int px = pxb + 64 * j;                                             \
        *(unsigned*)&inT[px * 40 + 2 * chp] = pack2(rv0[k][j], rv1[k][j]);       \
      }                                                                          \
    }                                                                            \
  }

  LOADR(0);
  for (int kc = 0; kc < 16; ++kc) {
    __syncthreads();
    WRITELDS();
    __syncthreads();
    if (kc < 15) LOADR(kc + 1);

    const bf16x8 a0 = *(const bf16x8*)(wbc + ((size_t)(kc * 32 + ln15)) * 32 + kg * 8);
    const bf16x8 a1 = *(const bf16x8*)(wbc + ((size_t)(kc * 32 + 16 + ln15)) * 32 + kg * 8);
#pragma unroll
    for (int f = 0; f < 4; ++f) {
      const int pxr = wid * 64 + f * 16 + ln15;
      const bf16x8 b = *(const bf16x8*)&inT[pxr * 40 + kg * 8];
      acc[0][f] = MFMA16(a0, b, acc[0][f]);
      acc[1][f] = MFMA16(a1, b, acc[1][f]);
    }
  }
#undef LOADR
#undef WRITELDS

#pragma unroll
  for (int mf = 0; mf < 2; ++mf) {
#pragma unroll
    for (int f = 0; f < 4; ++f) {
      const int px = px0 + wid * 64 + f * 16 + ln15;
      const int o = mf * 16 + kg * 4;
      *(f32x4*)(xT + ((size_t)n * 65536 + px) * 32 + o) = acc[mf][f];
    }
  }

#pragma unroll
  for (int mf = 0; mf < 2; ++mf) {
#pragma unroll
    for (int j = 0; j < 4; ++j) {
      float s = 0.f, q = 0.f;
#pragma unroll
      for (int f = 0; f < 4; ++f) { float v = acc[mf][f][j]; s += v; q += v * v; }
#pragma unroll
      for (int mk = 1; mk < 16; mk <<= 1) {
        s += __shfl_xor(s, mk);
        q += __shfl_xor(q, mk);
      }
      if (ln15 == 0) { red1[wid][kg][mf][j][0] = s; red1[wid][kg][mf][j][1] = q; }
    }
  }
  __syncthreads();
  if (tid < 32) {
    const int mf = tid >> 4, kgi = (tid >> 2) & 3, j = tid & 3;
    float s = red1[0][kgi][mf][j][0] + red1[1][kgi][mf][j][0]
            + red1[2][kgi][mf][j][0] + red1[3][kgi][mf][j][0];
    float q = red1[0][kgi][mf][j][1] + red1[1][kgi][mf][j][1]
            + red1[2][kgi][mf][j][1] + red1[3][kgi][mf][j][1];
    atomicAdd(&part1[tid], s);
    atomicAdd(&part1[32 + tid], q);
  }
}

// ============================================================================
// cbn1T: inline stats; normalize + lrelu; write padded bf16 T2.
// ============================================================================
__global__ __launch_bounds__(256) void cbn1T_kernel(
    const float* __restrict__ xT, const float* __restrict__ part1, float invN,
    const float* __restrict__ e1, const int* __restrict__ objs,
    unsigned short* __restrict__ T2)
{
  __shared__ float st[32][4];
  const int n = blockIdx.y;
  if (threadIdx.x < 32) {
    int y = objs[n];
    float s = part1[threadIdx.x], q = part1[32 + threadIdx.x];
    float mean = s * invN;
    st[threadIdx.x][0] = mean;
    st[threadIdx.x][1] = rsqrtf(q * invN - mean * mean + 1e-5f);
    st[threadIdx.x][2] = e1[(size_t)y * 64 + threadIdx.x];
    st[threadIdx.x][3] = e1[(size_t)y * 64 + 32 + threadIdx.x];
  }
  __syncthreads();
  const int pix = blockIdx.x * 256 + threadIdx.x;
  const int r = pix >> 8, c = pix & 255;
  const float* src = xT + ((size_t)n * 65536 + pix) * 32;
  unsigned short* dst = T2 + ((size_t)n * 66564 + (size_t)(r + 1) * 258 + (c + 1)) * 32;
  unsigned outw[16];
#pragma unroll
  for (int q = 0; q < 8; ++q) {
    float4 t = ((const float4*)src)[q];
    float v[4] = {t.x, t.y, t.z, t.w};
#pragma unroll
    for (int j = 0; j < 4; ++j) {
      int ch = q * 4 + j;
      float z = (v[j] - st[ch][0]) * st[ch][1] * st[ch][2] + st[ch][3];
      v[j] = z >= 0.f ? z : LEAK * z;
    }
    outw[2 * q]     = pack2(v[0], v[1]);
    outw[2 * q + 1] = pack2(v[2], v[3]);
  }
  uint4* d4 = (uint4*)dst;
#pragma unroll
  for (int q = 0; q < 4; ++q)
    d4[q] = make_uint4(outw[4*q], outw[4*q+1], outw[4*q+2], outw[4*q+3]);
}

// ============================================================================
// conv4T: 4x4 s2 p1 conv, stage-free. WM template + R19 NB batch-loop:
// each block processes NB consecutive n with per-n accumulators; A fragments
// load once per (tap,chunk) and feed NB x NT MFMAs (A-traffic / NB).
// ============================================================================
template <int C, int O, int H, int WM, int NB>
__global__ __launch_bounds__(256) void conv4T_kernel(
    const unsigned short* __restrict__ Tin, const unsigned short* __restrict__ wb,
    float* __restrict__ raw, float* __restrict__ part)
{
  constexpr int HIN2 = 2 * H + 2;
  constexpr int KC = C / 32;
  constexpr int WN4 = 4 / WM;
  constexpr int NT = WM;
  constexpr int LOGH = (H == 128 ? 7 : (H == 64 ? 6 : (H == 32 ? 5 : 4)));
  __shared__ float red[4][4][2][4][2];
  const int o0 = blockIdx.x * (WM * 32);
  const int strip = blockIdx.y;
  const int n0 = blockIdx.z * NB;
  const int tid = threadIdx.x, lane = tid & 63, wid = tid >> 6;
  const int wm = wid / WN4, wn = wid % WN4;
  const int ln15 = lane & 15, kg = lane >> 4;

  const unsigned short* inb[NB];
#pragma unroll
  for (int nb = 0; nb < NB; ++nb)
    inb[nb] = Tin + (size_t)(n0 + nb) * (HIN2 * HIN2) * C;

  f32x4 acc[NB][2][NT];
#pragma unroll
  for (int nb = 0; nb < NB; ++nb)
#pragma unroll
    for (int m = 0; m < 2; ++m)
#pragma unroll
      for (int nt = 0; nt < NT; ++nt) acc[nb][m][nt] = (f32x4){0.f, 0.f, 0.f, 0.f};

  int r_[NT], c_[NT];
#pragma unroll
  for (int nt = 0; nt < NT; ++nt) {
    const int gp = strip * 64 + (wn * NT + nt) * 16;
    r_[nt] = gp >> LOGH;
    c_[nt] = (gp & (H - 1)) + ln15;
  }

  for (int kc = 0; kc < KC; ++kc) {
    const int cb = kc * 32 + kg * 8;
#pragma unroll
    for (int tap = 0; tap < 16; ++tap) {
      const int ky = tap >> 2, kx = tap & 3;
      const unsigned short* ap = wb + ((size_t)tap * O + o0 + wm * 32 + ln15) * C + cb;
      bf16x8 a0 = *(const bf16x8*)ap;
      bf16x8 a1 = *(const bf16x8*)(ap + (size_t)16 * C);
#pragma unroll
      for (int nb = 0; nb < NB; ++nb) {
#pragma unroll
        for (int nt = 0; nt < NT; ++nt) {
          bf16x8 b = *(const bf16x8*)(inb[nb] + (size_t)((2 * r_[nt] + ky) * HIN2 + 2 * c_[nt] + kx) * C + cb);
          acc[nb][0][nt] = MFMA16(a0, b, acc[nb][0][nt]);
          acc[nb][1][nt] = MFMA16(a1, b, acc[nb][1][nt]);
        }
      }
    }
  }

#pragma unroll
  for (int nb = 0; nb < NB; ++nb)
#pragma unroll
    for (int mf = 0; mf < 2; ++mf) {
      const int o = o0 + wm * 32 + mf * 16 + kg * 4;
#pragma unroll
      for (int nt = 0; nt < NT; ++nt) {
        const int gp = strip * 64 + (wn * NT + nt) * 16 + ln15;
        *(f32x4*)(raw + ((size_t)(n0 + nb) * (H * H) + gp) * O + o) = acc[nb][mf][nt];
      }
    }

  // fused per-channel partials (sum over nb and nt; constant indices)
#pragma unroll
  for (int mf = 0; mf < 2; ++mf) {
#pragma unroll
    for (int j = 0; j < 4; ++j) {
      float s = 0.f, q = 0.f;
#pragma unroll
      for (int nb = 0; nb < NB; ++nb)
#pragma unroll
        for (int nt = 0; nt < NT; ++nt) { float v = acc[nb][mf][nt][j]; s += v; q += v * v; }
#pragma unroll
      for (int mk = 1; mk < 16; mk <<= 1) {
        s += __shfl_xor(s, mk);
        q += __shfl_xor(q, mk);
      }
      if (ln15 == 0) { red[wid][kg][mf][j][0] = s; red[wid][kg][mf][j][1] = q; }
    }
  }
  __syncthreads();
  if (tid < WM * 32) {
    const int wmi = tid >> 5, mf = (tid >> 4) & 1, kgi = (tid >> 2) & 3, j = tid & 3;
    float s = 0.f, q = 0.f;
#pragma unroll
    for (int w = 0; w < WN4; ++w) {
      s += red[wmi * WN4 + w][kgi][mf][j][0];
      q += red[wmi * WN4 + w][kgi][mf][j][1];
    }
    atomicAdd(&part[o0 + tid], s);
    atomicAdd(&part[O + o0 + tid], q);
  }
}

// ============================================================================
// cbnT: inline stats; normalize (+lrelu); write padded bf16.
// ============================================================================
template <int C, int H, int P2, int CSO, bool LRELU, bool LMAP>
__global__ __launch_bounds__(256) void cbnT_kernel(
    const float* __restrict__ raw, const float* __restrict__ part, float invN,
    const float* __restrict__ embed, const int* __restrict__ objs,
    unsigned short* __restrict__ Tout)
{
  constexpr int W2 = H + 2 * P2;
  constexpr int LOGH = (H == 128 ? 7 : (H == 64 ? 6 : (H == 32 ? 5 : 4)));
  const int n = blockIdx.y;
  const int y = objs[n];
  const int pix = blockIdx.x * 64 + (threadIdx.x >> 2);
  const int r = pix >> LOGH, c = pix & (H - 1);
  const float* src = raw + ((size_t)n * (H * H) + pix) * C;
  const size_t nb = LMAP ? (size_t)((n & 1) * 4 + (n >> 1)) * (W2 * W2) * CSO
                         : (size_t)n * (W2 * W2) * CSO;
  unsigned short* dst = Tout + nb + ((size_t)(r + P2) * W2 + c + P2) * CSO;
  const float* gam = embed + (size_t)y * 2 * C;
  const float* bet = gam + C;
  for (int cs = (threadIdx.x & 3); cs < C / 8; cs += 4) {
    float4 ps0 = ((const float4*)part)[cs * 2],       ps1 = ((const float4*)part)[cs * 2 + 1];
    float4 pq0 = ((const float4*)(part + C))[cs * 2], pq1 = ((const float4*)(part + C))[cs * 2 + 1];
    float4 g0 = ((const float4*)gam)[cs * 2], g1 = ((const float4*)gam)[cs * 2 + 1];
    float4 b0 = ((const float4*)bet)[cs * 2], b1 = ((const float4*)bet)[cs * 2 + 1];
    float4 v0 = ((const float4*)src)[cs * 2], v1 = ((const float4*)src)[cs * 2 + 1];
    float sv[8] = {ps0.x, ps0.y, ps0.z, ps0.w, ps1.x, ps1.y, ps1.z, ps1.w};
    float qv[8] = {pq0.x, pq0.y, pq0.z, pq0.w, pq1.x, pq1.y, pq1.z, pq1.w};
    float gv[8] = {g0.x, g0.y, g0.z, g0.w, g1.x, g1.y, g1.z, g1.w};
    float bv[8] = {b0.x, b0.y, b0.z, b0.w, b1.x, b1.y, b1.z, b1.w};
    float vv[8] = {v0.x, v0.y, v0.z, v0.w, v1.x, v1.y, v1.z, v1.w};
    float o_[8];
#pragma unroll
    for (int k = 0; k < 8; ++k) {
      float m = sv[k] * invN;
      float rs = rsqrtf(qv[k] * invN - m * m + 1e-5f);
      float z = (vv[k] - m) * rs * gv[k] + bv[k];
      o_[k] = (LRELU && z < 0.f) ? LEAK * z : z;
    }
    ((uint4*)dst)[cs] = make_uint4(pack2(o_[0], o_[1]), pack2(o_[2], o_[3]),
                                   pack2(o_[4], o_[5]), pack2(o_[6], o_[7]));
  }
}

// ============================================================================
// conv5L: 5x5 s1 p2 conv on 16x16 (ConvLSTM), stage-free, 1 chunk/block.
// ============================================================================
template <int O, int CS, int WM, int WN>
__global__ __launch_bounds__(256) void conv5L_kernel(
    const unsigned short* __restrict__ Lin, const unsigned short* __restrict__ wbf,
    float* __restrict__ pp, int kbeg, int slot0, size_t lin_tstr, size_t pp_tstr)
{
  constexpr int FN = 16 / WN;
  const int o0 = blockIdx.x * (WM * 32);
  const int b = blockIdx.y & 3, t = blockIdx.y >> 2;
  const int ks = blockIdx.z;
  const int tid = threadIdx.x, lane = tid & 63, wid = tid >> 6;
  const int wm = wid / WN, wn = wid % WN;
  const int ln15 = lane & 15, kg = lane >> 4;
  const unsigned short* inb = Lin + (size_t)t * lin_tstr + (size_t)b * 400 * CS;
  float* ppb = pp + (size_t)t * pp_tstr + ((size_t)(slot0 + ks) * 4 + b) * (256 * O);

  f32x4 acc[2][FN];
#pragma unroll
  for (int m = 0; m < 2; ++m)
#pragma unroll
    for (int nt = 0; nt < FN; ++nt) acc[m][nt] = (f32x4){0.f, 0.f, 0.f, 0.f};

  const int cb = (kbeg + ks) * 32 + kg * 8;
  for (int tap = 0; tap < 25; ++tap) {
    const int ty = tap / 5, tx = tap - 5 * ty;
    const unsigned short* ap = wbf + ((size_t)tap * O + o0 + wm * 32 + ln15) * CS + cb;
    bf16x8 a0 = *(const bf16x8*)ap;
    bf16x8 a1 = *(const bf16x8*)(ap + (size_t)16 * CS);
#pragma unroll
    for (int nt = 0; nt < FN; ++nt) {
      const int p = (wn * FN + nt) * 16 + ln15;
      const int prow = p >> 4, pcol = p & 15;
      bf16x8 bfv = *(const bf16x8*)(inb + (size_t)((prow + ty) * 20 + pcol + tx) * CS + cb);
      acc[0][nt] = MFMA16(a0, bfv, acc[0][nt]);
      acc[1][nt] = MFMA16(a1, bfv, acc[1][nt]);
    }
  }

#pragma unroll
  for (int mf = 0; mf < 2; ++mf) {
    const int o = o0 + wm * 32 + mf * 16 + kg * 4;
#pragma unroll
    for (int nt = 0; nt < FN; ++nt) {
      const int pix = (wn * FN + nt) * 16 + ln15;
      *(f32x4*)(ppb + (size_t)pix * O + o) = acc[mf][nt];
    }
  }
}

// ============================================================================
// lstm_pointT: sum KS pp-slots, gates -> (c,h).
// ============================================================================
template <int Hc, int CS, int CX, int CSN>
__global__ __launch_bounds__(256) void lstm_pointT_kernel(
    const float* __restrict__ pp, int KS, const float* __restrict__ bias,
    float* __restrict__ cT, unsigned short* __restrict__ own,
    unsigned short* __restrict__ nxt, float* __restrict__ fout)
{
  constexpr int C4 = Hc / 4;
  constexpr int O = 4 * Hc;
  constexpr int LOGC4 = (C4 == 32 ? 5 : 4);
  const int i = blockIdx.x * 256 + threadIdx.x;
  const int c4 = i & (C4 - 1);
  const int pix = (i >> LOGC4) & 255;
  const int b = i >> (LOGC4 + 8);

  float g[4][4];
#pragma unroll
  for (int gt = 0; gt < 4; ++gt)
#pragma unroll
    for (int j = 0; j < 4; ++j) g[gt][j] = 0.f;

  for (int ks = 0; ks < KS; ++ks) {
    const float* base = pp + (((size_t)(ks * 4 + b)) * 256 + pix) * O + c4 * 4;
#pragma unroll
    for (int gt = 0; gt < 4; ++gt) {
      float4 v = *(const float4*)(base + gt * Hc);
      g[gt][0] += v.x; g[gt][1] += v.y; g[gt][2] += v.z; g[gt][3] += v.w;
    }
  }
#pragma unroll
  for (int gt = 0; gt < 4; ++gt) {
    float4 bv = *(const float4*)(bias + gt * Hc + c4 * 4);
    g[gt][0] += bv.x; g[gt][1] += bv.y; g[gt][2] += bv.z; g[gt][3] += bv.w;
  }

  float* cp = cT + ((size_t)b * 256 + pix) * Hc + c4 * 4;
  float4 cold = *(const float4*)cp;
  float co[4] = {cold.x, cold.y, cold.z, cold.w};
  float hn[4];
#pragma unroll
  for (int j = 0; j < 4; ++j) {
    float si = 1.f / (1.f + expf(-g[0][j]));
    float sf = 1.f / (1.f + expf(-g[1][j]));
    float so = 1.f / (1.f + expf(-g[2][j]));
    float cn = sf * co[j] + si * tanhf(g[3][j]);
    co[j] = cn;
    hn[j] = so * tanhf(cn);
  }
  *(float4*)cp = make_float4(co[0], co[1], co[2], co[3]);

  const int prow = pix >> 4, pcol = pix & 15;
  const int ppix = (prow + 2) * 20 + pcol + 2;
  uint2 hb = make_uint2(pack2(hn[0], hn[1]), pack2(hn[2], hn[3]));
  if (own) *(uint2*)(own + ((size_t)b * 400 + ppix) * CS + CX + c4 * 4) = hb;
  if (nxt) *(uint2*)(nxt + ((size_t)b * 400 + ppix) * CSN + c4 * 4) = hb;
  if (fout) {
#pragma unroll
    for (int j = 0; j < 4; ++j)
      fout[((size_t)b * Hc + c4 * 4 + j) * 256 + pix] = hn[j];
  }
}

// ============================================================================
extern "C" void kernel_launch(void* const* d_in, const int* in_sizes, int n_in,
                              void* d_out, int out_size, void* d_ws, size_t ws_size,
                              hipStream_t stream)
{
  const float* h    = (const float*)d_in[0];
  const int*   objs = (const int*)  d_in[1];
  const float* c1w  = (const float*)d_in[3];
  const float* c2w  = (const float*)d_in[4];
  const float* c3w  = (const float*)d_in[5];
  const float* c4w  = (const float*)d_in[6];
  const float* c5w  = (const float*)d_in[7];
  const float* e1   = (const float*)d_in[8];
  const float* e2   = (const float*)d_in[9];
  const float* e3   = (const float*)d_in[10];
  const float* e4   = (const float*)d_in[11];
  const float* e5   = (const float*)d_in[12];
  const float* lw0  = (const float*)d_in[13];
  const float* lb0  = (const float*)d_in[14];
  const float* lw1  = (const float*)d_in[15];
  const float* lb1  = (const float*)d_in[16];
  const float* lw2  = (const float*)d_in[17];
  const float* lb2  = (const float*)d_in[18];

  char* p = (char*)d_ws;
  auto alloc = [&](size_t bytes) { char* r = p; p += (bytes + 255) & ~(size_t)255; return r; };
  // ---- non-zeroed ----
  float* x1T  = (float*)alloc((size_t)8 * 65536 * 32 * 4);
  float* raw2 = (float*)alloc((size_t)8 * 16384 * 64 * 4);
  float* raw3 = (float*)alloc((size_t)8 * 4096 * 128 * 4);
  float* raw4 = (float*)alloc((size_t)8 * 1024 * 256 * 4);
  float* raw5 = (float*)alloc((size_t)8 * 256 * 512 * 4);
  float* pp   = (float*)alloc((size_t)2 * 20 * 4 * 256 * 512 * 4);   // 84 MB
  unsigned short* wb1  = (unsigned short*)alloc((size_t)32 * 512 * 2);
  unsigned short* wb2  = (unsigned short*)alloc((size_t)16 * 64 * 32 * 2);
  unsigned short* wb3  = (unsigned short*)alloc((size_t)16 * 128 * 64 * 2);
  unsigned short* wb4  = (unsigned short*)alloc((size_t)16 * 256 * 128 * 2);
  unsigned short* wb5  = (unsigned short*)alloc((size_t)16 * 512 * 256 * 2);
  unsigned short* wbf0 = (unsigned short*)alloc((size_t)25 * 512 * 640 * 2);
  unsigned short* wbf1 = (unsigned short*)alloc((size_t)25 * 256 * 192 * 2);
  unsigned short* wbf2 = (unsigned short*)alloc((size_t)25 * 256 * 128 * 2);
  // ---- contiguous ZERO region (single memset) ----
  char* zbase = p;
  unsigned short* T2 = (unsigned short*)alloc((size_t)8 * 66564 * 32 * 2);
  unsigned short* T3 = (unsigned short*)alloc((size_t)8 * 16900 * 64 * 2);
  unsigned short* T4 = (unsigned short*)alloc((size_t)8 * 4356 * 128 * 2);
  unsigned short* T5 = (unsigned short*)alloc((size_t)8 * 1156 * 256 * 2);
  unsigned short* L0in = (unsigned short*)alloc((size_t)2 * 4 * 400 * 640 * 2);
  unsigned short* L1in = (unsigned short*)alloc((size_t)2 * 4 * 400 * 192 * 2);
  unsigned short* L2in = (unsigned short*)alloc((size_t)2 * 4 * 400 * 128 * 2);
  float* cT0 = (float*)alloc((size_t)4 * 256 * 128 * 4);
  float* cT1 = (float*)alloc((size_t)4 * 256 * 64 * 4);
  float* cT2 = (float*)alloc((size_t)4 * 256 * 64 * 4);
  float* part1 = (float*)alloc(2 * 32 * 4);
  float* part2 = (float*)alloc(2 * 64 * 4);
  float* part3 = (float*)alloc(2 * 128 * 4);
  float* part4 = (float*)alloc(2 * 256 * 4);
  float* part5 = (float*)alloc(2 * 512 * 4);
  size_t zsize = (size_t)(p - zbase);

  hipMemsetAsync(zbase, 0, zsize, stream);
  wprepT_kernel<<<2344, 256, 0, stream>>>(
      c1w, c2w, c3w, c4w, c5w, lw0, lw1, lw2,
      wb1, wb2, wb3, wb4, wb5, wbf0, wbf1, wbf2);

  // ---- stage 1 ----
  conv1M_kernel<<<dim3(256, 8), 256, 0, stream>>>(h, wb1, x1T, part1);
  cbn1T_kernel<<<dim3(256, 8), 256, 0, stream>>>(x1T, part1, 1.f / (float)(8 * 65536), e1, objs, T2);

  // ---- stages 2-5 (NB batch-loop for 3/4/5) ----
  conv4T_kernel<32, 64, 128, 2, 1><<<dim3(1, 256, 8), 256, 0, stream>>>(T2, wb2, raw2, part2);
  cbnT_kernel<64, 128, 1, 64, true, false><<<dim3(256, 8), 256, 0, stream>>>(
      raw2, part2, 1.f / (float)(8 * 16384), e2, objs, T3);

  conv4T_kernel<64, 128, 64, 2, 2><<<dim3(2, 64, 4), 256, 0, stream>>>(T3, wb3, raw3, part3);
  cbnT_kernel<128, 64, 1, 128, true, false><<<dim3(64, 8), 256, 0, stream>>>(
      raw3, part3, 1.f / (float)(8 * 4096), e3, objs, T4);

  conv4T_kernel<128, 256, 32, 1, 2><<<dim3(8, 16, 4), 256, 0, stream>>>(T4, wb4, raw4, part4);
  cbnT_kernel<256, 32, 1, 256, false, false><<<dim3(16, 8), 256, 0, stream>>>(
      raw4, part4, 1.f / (float)(8 * 1024), e4, objs, T5);

  conv4T_kernel<256, 512, 16, 1, 2><<<dim3(16, 4, 4), 256, 0, stream>>>(T5, wb5, raw5, part5);
  cbnT_kernel<512, 16, 2, 640, false, true><<<dim3(4, 8), 256, 0, stream>>>(
      raw5, part5, 1.f / (float)(8 * 256), e5, objs, L0in);

  // ---- ConvLSTM 0 (C=640: x=16 chunks, h=4 chunks) ----
  {
    const size_t LINT = (size_t)4 * 400 * 640;
    const size_t PPT  = (size_t)20 * 4 * 256 * 512;
    conv5L_kernel<512, 640, 2, 2><<<dim3(8, 8, 16), 256, 0, stream>>>(
        L0in, wbf0, pp, 0, 0, LINT, PPT);
    lstm_pointT_kernel<128, 640, 512, 192><<<128, 256, 0, stream>>>(
        pp, 16, lb0, cT0, L0in + LINT, L1in, nullptr);
    conv5L_kernel<512, 640, 2, 2><<<dim3(8, 4, 4), 256, 0, stream>>>(
        L0in + LINT, wbf0, pp + PPT, 16, 16, 0, 0);
    lstm_pointT_kernel<128, 640, 512, 192><<<128, 256, 0, stream>>>(
        pp + PPT, 20, lb0, cT0, nullptr, L1in + (size_t)4 * 400 * 192, nullptr);
  }

  // ---- ConvLSTM 1 (C=192: x=4, h=2) ----
  {
    const size_t LINT = (size_t)4 * 400 * 192;
    const size_t PPT  = (size_t)6 * 4 * 256 * 256;
    conv5L_kernel<256, 192, 1, 4><<<dim3(8, 8, 4), 256, 0, stream>>>(
        L1in, wbf1, pp, 0, 0, LINT, PPT);
    lstm_pointT_kernel<64, 192, 128, 128><<<64, 256, 0, stream>>>(
        pp, 4, lb1, cT1, L1in + LINT, L2in, nullptr);
    conv5L_kernel<256, 192, 1, 4><<<dim3(8, 4, 2), 256, 0, stream>>>(
        L1in + LINT, wbf1, pp + PPT, 4, 4, 0, 0);
    lstm_pointT_kernel<64, 192, 128, 128><<<64, 256, 0, stream>>>(
        pp + PPT, 6, lb1, cT1, nullptr, L2in + (size_t)4 * 400 * 128, nullptr);
  }

  // ---- ConvLSTM 2 (C=128: x=2, h=2), final h -> d_out ----
  {
    const size_t LINT = (size_t)4 * 400 * 128;
    const size_t PPT  = (size_t)4 * 4 * 256 * 256;
    conv5L_kernel<256, 128, 1, 4><<<dim3(8, 8, 2), 256, 0, stream>>>(
        L2in, wbf2, pp, 0, 0, LINT, PPT);
    lstm_pointT_kernel<64, 128, 64, 1><<<64, 256, 0, stream>>>(
        pp, 2, lb2, cT2, L2in + LINT, nullptr, nullptr);
    conv5L_kernel<256, 128, 1, 4><<<dim3(8, 4, 2), 256, 0, stream>>>(
        L2in + LINT, wbf2, pp + PPT, 2, 2, 0, 0);
    lstm_pointT_kernel<64, 128, 64, 1><<<64, 256, 0, stream>>>(
        pp + PPT, 4, lb2, cT2, nullptr, nullptr, (float*)d_out);
  }
}